// Round 2
// baseline (648.847 us; speedup 1.0000x reference)
//
#include <hip/hip_runtime.h>
#include <hip/hip_bf16.h>

#define B_ 8
#define T_ 243
#define J_ 17
#define C_ 512
#define H_ 8
#define HD_ 64
#define M_ (B_*T_*J_)            // 33048
#define SCALE_ 0.125f
#define QKV_ELEMS (B_*H_*J_*T_*HD_)  // 16,920,576

typedef __attribute__((ext_vector_type(4))) float f32x4;
typedef __attribute__((ext_vector_type(8))) short bf16x8;

__device__ __forceinline__ ushort f2bf(float f) {
  union { float f; unsigned u; } v; v.f = f;
  unsigned r = v.u + 0x7FFFu + ((v.u >> 16) & 1u);
  return (ushort)(r >> 16);
}
__device__ __forceinline__ float bf2f(ushort u) {
  union { unsigned u; float f; } v; v.u = (unsigned)u << 16; return v.f;
}

// ---------------- f32 -> bf16 convert (8 elems/thread) ----------------
__global__ __launch_bounds__(256) void cvt_kernel(const float* __restrict__ in,
                                                  ushort* __restrict__ out, int n8) {
  int i = blockIdx.x * 256 + threadIdx.x;
  if (i >= n8) return;
  const float4* p = (const float4*)in + (size_t)i * 2;
  float4 v0 = p[0], v1 = p[1];
  bf16x8 o;
  o[0] = (short)f2bf(v0.x); o[1] = (short)f2bf(v0.y);
  o[2] = (short)f2bf(v0.z); o[3] = (short)f2bf(v0.w);
  o[4] = (short)f2bf(v1.x); o[5] = (short)f2bf(v1.y);
  o[6] = (short)f2bf(v1.z); o[7] = (short)f2bf(v1.w);
  *(bf16x8*)(out + (size_t)i * 8) = o;
}

// ---------------- bf16 GEMM: C[M,N] = A[M,K=512] @ Bm[N,K=512]^T ----------------
template<int EPI>
__global__ __launch_bounds__(256) void gemm_bt(
    const ushort* __restrict__ A, const ushort* __restrict__ Bm,
    ushort* __restrict__ qkvout, float* __restrict__ fout,
    const float* __restrict__ bias)
{
  __shared__ ushort As[128 * 64];
  __shared__ ushort Bs[128 * 64];
  const int tid = threadIdx.x;
  const int lane = tid & 63;
  const int lo = lane & 15, hi = lane >> 4;
  const int wave = tid >> 6;
  const int wr = wave >> 1, wc = wave & 1;
  const int mt = blockIdx.x, nt = blockIdx.y;

  f32x4 acc[4][4] = {};

  for (int ks = 0; ks < 8; ++ks) {
    const int k0 = ks * 64;
    bf16x8 ra[4], rb[4];
    #pragma unroll
    for (int i = 0; i < 4; ++i) {
      int c = tid + i * 256;
      int row = c >> 3, col8 = c & 7;
      int arow = mt * 128 + row; if (arow > M_ - 1) arow = M_ - 1;
      ra[i] = *(const bf16x8*)(A + (size_t)arow * 512 + k0 + col8 * 8);
      int brow = nt * 128 + row;
      rb[i] = *(const bf16x8*)(Bm + (size_t)brow * 512 + k0 + col8 * 8);
    }
    __syncthreads();
    #pragma unroll
    for (int i = 0; i < 4; ++i) {
      int c = tid + i * 256;
      int row = c >> 3, col8 = c & 7;
      int sc = col8 ^ (row & 7);
      *(bf16x8*)(As + row * 64 + sc * 8) = ra[i];
      *(bf16x8*)(Bs + row * 64 + sc * 8) = rb[i];
    }
    __syncthreads();
    #pragma unroll
    for (int kk = 0; kk < 2; ++kk) {
      bf16x8 af[4], bf[4];
      #pragma unroll
      for (int mf = 0; mf < 4; ++mf) {
        int row = wr * 64 + mf * 16 + lo;
        int sc = (kk * 4 + hi) ^ (row & 7);
        af[mf] = *(const bf16x8*)(As + row * 64 + sc * 8);
      }
      #pragma unroll
      for (int nf = 0; nf < 4; ++nf) {
        int row = wc * 64 + nf * 16 + lo;
        int sc = (kk * 4 + hi) ^ (row & 7);
        bf[nf] = *(const bf16x8*)(Bs + row * 64 + sc * 8);
      }
      #pragma unroll
      for (int mf = 0; mf < 4; ++mf)
        #pragma unroll
        for (int nf = 0; nf < 4; ++nf)
          acc[mf][nf] = __builtin_amdgcn_mfma_f32_16x16x32_bf16(af[mf], bf[nf], acc[mf][nf], 0, 0, 0);
    }
  }

  if (EPI == 0) {
    const int which = nt >> 2;                 // 0=q 1=k 2=v
    const int h = (nt * 2 + wc) & 7;
    const float scale = (which == 0) ? SCALE_ : 1.0f;
    ushort* basep = qkvout + (size_t)which * QKV_ELEMS;
    #pragma unroll
    for (int mf = 0; mf < 4; ++mf) {
      #pragma unroll
      for (int i = 0; i < 4; ++i) {
        int r = mt * 128 + wr * 64 + mf * 16 + hi * 4 + i;
        if (r >= M_) continue;
        int b = r / (T_ * J_);
        int rem = r - b * (T_ * J_);
        int t = rem / J_;
        int j = rem - t * J_;
        size_t rowoff = (((size_t)(b * H_ + h) * J_ + j) * T_ + t) * HD_;
        #pragma unroll
        for (int nf = 0; nf < 4; ++nf) {
          int hd = nf * 16 + lo;
          basep[rowoff + hd] = f2bf(acc[mf][nf][i] * scale);
        }
      }
    }
  } else {
    #pragma unroll
    for (int mf = 0; mf < 4; ++mf) {
      #pragma unroll
      for (int i = 0; i < 4; ++i) {
        int r = mt * 128 + wr * 64 + mf * 16 + hi * 4 + i;
        if (r >= M_) continue;
        #pragma unroll
        for (int nf = 0; nf < 4; ++nf) {
          int n = nt * 128 + wc * 64 + nf * 16 + lo;
          fout[(size_t)r * C_ + n] = acc[mf][nf][i] + bias[n];
        }
      }
    }
  }
}

// ---------------- flash: pure w*softmax(QK^T)@V, one block per (b,h,j,rt) ----------------
// writes O2[bhj][t][hd] bf16 (already scaled by w)
__global__ __launch_bounds__(256, 3) void flash_kernel(
    const ushort* __restrict__ q, const ushort* __restrict__ k,
    const ushort* __restrict__ v, const float* __restrict__ wptr,
    ushort* __restrict__ O2)
{
  __shared__ ushort Vt[64 * 256];   // transposed V [hd][s], swizzled (32KB)
  __shared__ ushort Ps[64 * 128];   // P half-tile [row][s_local], swizzled (16KB)
  __shared__ float red0[2][64];
  __shared__ float red1[2][64];

  const int tid = threadIdx.x;
  const int lane = tid & 63;
  const int lo = lane & 15, hi = lane >> 4;
  const int wave = tid >> 6;
  const int wr = wave >> 1, wc = wave & 1;
  const int bid = blockIdx.x;
  // XCD-chunked remap: grid 4352 = 8 * 544; rt-siblings land on the same XCD
  const int workid = (bid & 7) * 544 + (bid >> 3);
  const int bhj = workid >> 2, rt = workid & 3;
  const float w = wptr[0];
  const size_t kvbase = (size_t)bhj * (T_ * HD_);
  const int r0 = rt * 64;

  // stage V transposed + zero-padded
  #pragma unroll
  for (int it = 0; it < 8; ++it) {
    int c = tid + it * 256;
    int s = c >> 3, hd0 = (c & 7) * 8;
    bf16x8 val = {};
    if (s < T_) val = *(const bf16x8*)(v + kvbase + (size_t)s * HD_ + hd0);
    #pragma unroll
    for (int e = 0; e < 8; ++e) {
      int row = hd0 + e;
      int chunk = (s >> 3) ^ (row & 7);
      Vt[row * 256 + chunk * 8 + (s & 7)] = (ushort)val[e];
    }
  }
  __syncthreads();

  // Q fragments direct from global
  bf16x8 aq[2][2];
  #pragma unroll
  for (int mf = 0; mf < 2; ++mf) {
    int t = r0 + wr * 32 + mf * 16 + lo; if (t > T_ - 1) t = T_ - 1;
    #pragma unroll
    for (int kk = 0; kk < 2; ++kk)
      aq[mf][kk] = *(const bf16x8*)(q + kvbase + (size_t)t * HD_ + kk * 32 + hi * 8);
  }

  // QK^T
  f32x4 acc[2][8] = {};
  #pragma unroll
  for (int nf = 0; nf < 8; ++nf) {
    int s = wc * 128 + nf * 16 + lo; if (s > T_ - 1) s = T_ - 1;
    #pragma unroll
    for (int kk = 0; kk < 2; ++kk) {
      bf16x8 bk = *(const bf16x8*)(k + kvbase + (size_t)s * HD_ + kk * 32 + hi * 8);
      #pragma unroll
      for (int mf = 0; mf < 2; ++mf)
        acc[mf][nf] = __builtin_amdgcn_mfma_f32_16x16x32_bf16(aq[mf][kk], bk, acc[mf][nf], 0, 0, 0);
    }
  }

  // row max (mask s >= 243)
  float rmax[2][4];
  #pragma unroll
  for (int mf = 0; mf < 2; ++mf)
    #pragma unroll
    for (int i = 0; i < 4; ++i) {
      float m = -1e30f;
      #pragma unroll
      for (int nf = 0; nf < 8; ++nf) {
        int s = wc * 128 + nf * 16 + lo;
        if (s < T_) m = fmaxf(m, acc[mf][nf][i]);
      }
      rmax[mf][i] = m;
    }
  #pragma unroll
  for (int d = 1; d < 16; d <<= 1)
    #pragma unroll
    for (int mf = 0; mf < 2; ++mf)
      #pragma unroll
      for (int i = 0; i < 4; ++i)
        rmax[mf][i] = fmaxf(rmax[mf][i], __shfl_xor(rmax[mf][i], d, 64));
  if (lo == 0) {
    #pragma unroll
    for (int mf = 0; mf < 2; ++mf)
      #pragma unroll
      for (int i = 0; i < 4; ++i)
        red0[wc][wr * 32 + mf * 16 + hi * 4 + i] = rmax[mf][i];
  }
  __syncthreads();

  // exp + row sum
  float rsum[2][4];
  #pragma unroll
  for (int mf = 0; mf < 2; ++mf)
    #pragma unroll
    for (int i = 0; i < 4; ++i) {
      float Mx = fmaxf(rmax[mf][i], red0[wc ^ 1][wr * 32 + mf * 16 + hi * 4 + i]);
      float ssum = 0.f;
      #pragma unroll
      for (int nf = 0; nf < 8; ++nf) {
        int s = wc * 128 + nf * 16 + lo;
        float e = 0.f;
        if (s < T_) e = __expf(acc[mf][nf][i] - Mx);
        acc[mf][nf][i] = e;
        ssum += e;
      }
      rsum[mf][i] = ssum;
    }
  #pragma unroll
  for (int d = 1; d < 16; d <<= 1)
    #pragma unroll
    for (int mf = 0; mf < 2; ++mf)
      #pragma unroll
      for (int i = 0; i < 4; ++i)
        rsum[mf][i] += __shfl_xor(rsum[mf][i], d, 64);
  if (lo == 0) {
    #pragma unroll
    for (int mf = 0; mf < 2; ++mf)
      #pragma unroll
      for (int i = 0; i < 4; ++i)
        red1[wc][wr * 32 + mf * 16 + hi * 4 + i] = rsum[mf][i];
  }
  __syncthreads();

  float pinv[2][4];
  #pragma unroll
  for (int mf = 0; mf < 2; ++mf)
    #pragma unroll
    for (int i = 0; i < 4; ++i) {
      float L = rsum[mf][i] + red1[wc ^ 1][wr * 32 + mf * 16 + hi * 4 + i];
      pinv[mf][i] = w / L;   // fold blend weight into P
    }

  // PV in two s-halves through half-size Ps
  f32x4 oacc[2][2] = {};
  #pragma unroll
  for (int h2 = 0; h2 < 2; ++h2) {
    __syncthreads();
    if (wc == h2) {
      #pragma unroll
      for (int mf = 0; mf < 2; ++mf)
        #pragma unroll
        for (int i = 0; i < 4; ++i) {
          int row_local = wr * 32 + mf * 16 + hi * 4 + i;
          float pw = pinv[mf][i];
          #pragma unroll
          for (int nf = 0; nf < 8; ++nf) {
            int s = h2 * 128 + nf * 16 + lo;
            float p = (s < T_) ? acc[mf][nf][i] * pw : 0.f;
            int s_local = nf * 16 + lo;
            int chunk = (s_local >> 3) ^ (row_local & 7);
            Ps[row_local * 128 + chunk * 8 + (s_local & 7)] = f2bf(p);
          }
        }
    }
    __syncthreads();
    #pragma unroll
    for (int kk = 0; kk < 4; ++kk) {
      bf16x8 ap[2], bv[2];
      #pragma unroll
      for (int mf = 0; mf < 2; ++mf) {
        int row = wr * 32 + mf * 16 + lo;
        int chunk = (kk * 4 + hi) ^ (row & 7);
        ap[mf] = *(const bf16x8*)(Ps + row * 128 + chunk * 8);
      }
      #pragma unroll
      for (int nf = 0; nf < 2; ++nf) {
        int row = wc * 32 + nf * 16 + lo;   // hd
        int chunk = ((h2 * 4 + kk) * 4 + hi) ^ (row & 7);
        bv[nf] = *(const bf16x8*)(Vt + row * 256 + chunk * 8);
      }
      #pragma unroll
      for (int mf = 0; mf < 2; ++mf)
        #pragma unroll
        for (int nf = 0; nf < 2; ++nf)
          oacc[mf][nf] = __builtin_amdgcn_mfma_f32_16x16x32_bf16(ap[mf], bv[nf], oacc[mf][nf], 0, 0, 0);
    }
  }

  // write O2 [bhj][t][hd] (coalesced)
  #pragma unroll
  for (int mf = 0; mf < 2; ++mf)
    #pragma unroll
    for (int i = 0; i < 4; ++i) {
      int t = r0 + wr * 32 + mf * 16 + hi * 4 + i;
      if (t >= T_) continue;
      size_t rowoff = ((size_t)bhj * T_ + t) * HD_;
      #pragma unroll
      for (int nf = 0; nf < 2; ++nf) {
        int hd = wc * 32 + nf * 16 + lo;
        O2[rowoff + hd] = f2bf(oacc[mf][nf][i]);
      }
    }
}

// ---------------- amv: O = (1-w)*(am@V) + O2, one block per (b,h,j) ----------------
// streams am (f32, coalesced flat), writes final O in [B,T,J,C] bf16
__global__ __launch_bounds__(256, 2) void amv_kernel(
    const float* __restrict__ am, const ushort* __restrict__ v,
    const ushort* __restrict__ o2, const float* __restrict__ wptr,
    ushort* __restrict__ outO)
{
  __shared__ ushort Vt[64 * 256];   // transposed V [hd][s], swizzled
  __shared__ ushort amS[64 * 256];  // am tile [t_local][s], swizzled

  const int tid = threadIdx.x;
  const int lane = tid & 63;
  const int lo = lane & 15, hi = lane >> 4;
  const int wave = tid >> 6;
  const int wr = wave >> 1, wc = wave & 1;
  const int bhj = blockIdx.x;
  const int bh = bhj / J_, j = bhj - bh * J_;
  const int b = bh >> 3, h = bh & 7;
  const float wb = 1.0f - wptr[0];
  const size_t kvbase = (size_t)bhj * (T_ * HD_);
  const size_t ambase = (size_t)bhj * (T_ * T_);

  // stage V transposed + zero-padded
  #pragma unroll
  for (int it = 0; it < 8; ++it) {
    int c = tid + it * 256;
    int s = c >> 3, hd0 = (c & 7) * 8;
    bf16x8 val = {};
    if (s < T_) val = *(const bf16x8*)(v + kvbase + (size_t)s * HD_ + hd0);
    #pragma unroll
    for (int e = 0; e < 8; ++e) {
      int row = hd0 + e;
      int chunk = (s >> 3) ^ (row & 7);
      Vt[row * 256 + chunk * 8 + (s & 7)] = (ushort)val[e];
    }
  }

  for (int rt = 0; rt < 4; ++rt) {
    const int r0 = rt * 64;
    __syncthreads();   // covers Vt stage (rt=0) and prior amS reads (rt>0)
    // stage am tile: dest-driven, reads are flat-coalesced dwords
    for (int idx = tid; idx < 16384; idx += 256) {
      int row = idx >> 8, col = idx & 255;
      int t = r0 + row;
      float f = (col < T_ && t < T_) ? am[ambase + (size_t)t * T_ + col] : 0.f;
      int chunk = (col >> 3) ^ (row & 7);
      amS[row * 256 + chunk * 8 + (col & 7)] = f2bf(f);
    }
    __syncthreads();

    f32x4 acc[2][2] = {};
    #pragma unroll
    for (int kk = 0; kk < 8; ++kk) {
      bf16x8 aa[2], bv[2];
      #pragma unroll
      for (int mf = 0; mf < 2; ++mf) {
        int row = wr * 32 + mf * 16 + lo;
        int chunk = (kk * 4 + hi) ^ (row & 7);
        aa[mf] = *(const bf16x8*)(amS + row * 256 + chunk * 8);
      }
      #pragma unroll
      for (int nf = 0; nf < 2; ++nf) {
        int row = wc * 32 + nf * 16 + lo;   // hd
        int chunk = (kk * 4 + hi) ^ (row & 7);
        bv[nf] = *(const bf16x8*)(Vt + row * 256 + chunk * 8);
      }
      #pragma unroll
      for (int mf = 0; mf < 2; ++mf)
        #pragma unroll
        for (int nf = 0; nf < 2; ++nf)
          acc[mf][nf] = __builtin_amdgcn_mfma_f32_16x16x32_bf16(aa[mf], bv[nf], acc[mf][nf], 0, 0, 0);
    }

    // epilogue: blend with O2 (w*SV) and write final O [B,T,J,C]
    #pragma unroll
    for (int mf = 0; mf < 2; ++mf)
      #pragma unroll
      for (int i = 0; i < 4; ++i) {
        int t = r0 + wr * 32 + mf * 16 + hi * 4 + i;
        if (t >= T_) continue;
        size_t o2row = ((size_t)bhj * T_ + t) * HD_;
        size_t orow = ((size_t)(b * T_ + t) * J_ + j) * C_ + h * HD_;
        #pragma unroll
        for (int nf = 0; nf < 2; ++nf) {
          int hd = wc * 32 + nf * 16 + lo;
          outO[orow + hd] = f2bf(wb * acc[mf][nf][i] + bf2f(o2[o2row + hd]));
        }
      }
  }
}

// ---------------- launcher ----------------
extern "C" void kernel_launch(void* const* d_in, const int* in_sizes, int n_in,
                              void* d_out, int out_size, void* d_ws, size_t ws_size,
                              hipStream_t stream) {
  const float* x      = (const float*)d_in[0];
  const float* am     = (const float*)d_in[1];
  const float* weight = (const float*)d_in[2];
  const float* w_qkv  = (const float*)d_in[3];
  const float* w_proj = (const float*)d_in[4];
  const float* b_proj = (const float*)d_in[5];
  float* outp = (float*)d_out;

  char* ws = (char*)d_ws;
  ushort* wqkv_bf  = (ushort*)(ws);                  // 1,572,864 B
  ushort* wproj_bf = (ushort*)(ws + 1572864);        //   524,288 B
  ushort* xbf      = (ushort*)(ws + 2097152);        // 33,841,152 B (x bf16, reused as O2)
  ushort* qws      = (ushort*)(ws + 35938304);       // q, reused as final O [B,T,J,C]
  ushort* kws = qws + QKV_ELEMS;
  ushort* vws = kws + QKV_ELEMS;
  if (ws_size < 137461760ull) return;

  cvt_kernel<<<8262, 256, 0, stream>>>(x, xbf, 2115072);
  cvt_kernel<<<384, 256, 0, stream>>>(w_qkv, wqkv_bf, 98304);
  cvt_kernel<<<128, 256, 0, stream>>>(w_proj, wproj_bf, 32768);

  gemm_bt<0><<<dim3(259, 12), 256, 0, stream>>>(xbf, wqkv_bf, qws, nullptr, nullptr);

  // flash: q,k,v -> O2 (= w * softmax@V) into xbf region (x no longer needed)
  flash_kernel<<<4352, 256, 0, stream>>>(qws, kws, vws, weight, xbf);

  // amv: am,V,O2 -> final O into qws region (q no longer needed)
  amv_kernel<<<1088, 256, 0, stream>>>(am, vws, xbf, weight, qws);

  gemm_bt<1><<<dim3(259, 4), 256, 0, stream>>>(qws, wproj_bf, nullptr, outp, b_proj);
}

// Round 3
// 369.404 us; speedup vs baseline: 1.7565x; 1.7565x over previous
//
#include <hip/hip_runtime.h>
#include <hip/hip_bf16.h>

#define B_ 8
#define T_ 243
#define J_ 17
#define C_ 512
#define H_ 8
#define HD_ 64
#define M_ (B_*T_*J_)            // 33048
#define SCALE_ 0.125f
#define QKV_ELEMS (B_*H_*J_*T_*HD_)  // 16,920,576

typedef __attribute__((ext_vector_type(4))) float f32x4;
typedef __attribute__((ext_vector_type(8))) short bf16x8;

__device__ __forceinline__ ushort f2bf(float f) {
  union { float f; unsigned u; } v; v.f = f;
  unsigned r = v.u + 0x7FFFu + ((v.u >> 16) & 1u);
  return (ushort)(r >> 16);
}
__device__ __forceinline__ float bf2f(ushort u) {
  union { unsigned u; float f; } v; v.u = (unsigned)u << 16; return v.f;
}

// ---------------- f32 -> bf16 convert (8 elems/thread) ----------------
__global__ __launch_bounds__(256) void cvt_kernel(const float* __restrict__ in,
                                                  ushort* __restrict__ out, int n8) {
  int i = blockIdx.x * 256 + threadIdx.x;
  if (i >= n8) return;
  const float4* p = (const float4*)in + (size_t)i * 2;
  float4 v0 = p[0], v1 = p[1];
  bf16x8 o;
  o[0] = (short)f2bf(v0.x); o[1] = (short)f2bf(v0.y);
  o[2] = (short)f2bf(v0.z); o[3] = (short)f2bf(v0.w);
  o[4] = (short)f2bf(v1.x); o[5] = (short)f2bf(v1.y);
  o[6] = (short)f2bf(v1.z); o[7] = (short)f2bf(v1.w);
  *(bf16x8*)(out + (size_t)i * 8) = o;
}

// ---------------- bf16 GEMM: C[M,N] = A[M,K=512] @ Bm[N,K=512]^T ----------------
template<int EPI>
__global__ __launch_bounds__(256) void gemm_bt(
    const ushort* __restrict__ A, const ushort* __restrict__ Bm,
    ushort* __restrict__ qkvout, float* __restrict__ fout,
    const float* __restrict__ bias)
{
  __shared__ ushort As[128 * 64];
  __shared__ ushort Bs[128 * 64];
  const int tid = threadIdx.x;
  const int lane = tid & 63;
  const int lo = lane & 15, hi = lane >> 4;
  const int wave = tid >> 6;
  const int wr = wave >> 1, wc = wave & 1;
  const int mt = blockIdx.x, nt = blockIdx.y;

  f32x4 acc[4][4] = {};

  for (int ks = 0; ks < 8; ++ks) {
    const int k0 = ks * 64;
    bf16x8 ra[4], rb[4];
    #pragma unroll
    for (int i = 0; i < 4; ++i) {
      int c = tid + i * 256;
      int row = c >> 3, col8 = c & 7;
      int arow = mt * 128 + row; if (arow > M_ - 1) arow = M_ - 1;
      ra[i] = *(const bf16x8*)(A + (size_t)arow * 512 + k0 + col8 * 8);
      int brow = nt * 128 + row;
      rb[i] = *(const bf16x8*)(Bm + (size_t)brow * 512 + k0 + col8 * 8);
    }
    __syncthreads();
    #pragma unroll
    for (int i = 0; i < 4; ++i) {
      int c = tid + i * 256;
      int row = c >> 3, col8 = c & 7;
      int sc = col8 ^ (row & 7);
      *(bf16x8*)(As + row * 64 + sc * 8) = ra[i];
      *(bf16x8*)(Bs + row * 64 + sc * 8) = rb[i];
    }
    __syncthreads();
    #pragma unroll
    for (int kk = 0; kk < 2; ++kk) {
      bf16x8 af[4], bf[4];
      #pragma unroll
      for (int mf = 0; mf < 4; ++mf) {
        int row = wr * 64 + mf * 16 + lo;
        int sc = (kk * 4 + hi) ^ (row & 7);
        af[mf] = *(const bf16x8*)(As + row * 64 + sc * 8);
      }
      #pragma unroll
      for (int nf = 0; nf < 4; ++nf) {
        int row = wc * 64 + nf * 16 + lo;
        int sc = (kk * 4 + hi) ^ (row & 7);
        bf[nf] = *(const bf16x8*)(Bs + row * 64 + sc * 8);
      }
      #pragma unroll
      for (int mf = 0; mf < 4; ++mf)
        #pragma unroll
        for (int nf = 0; nf < 4; ++nf)
          acc[mf][nf] = __builtin_amdgcn_mfma_f32_16x16x32_bf16(af[mf], bf[nf], acc[mf][nf], 0, 0, 0);
    }
  }

  if (EPI == 0) {
    const int which = nt >> 2;                 // 0=q 1=k 2=v
    const int h = (nt * 2 + wc) & 7;
    const float scale = (which == 0) ? SCALE_ : 1.0f;
    ushort* basep = qkvout + (size_t)which * QKV_ELEMS;
    #pragma unroll
    for (int mf = 0; mf < 4; ++mf) {
      #pragma unroll
      for (int i = 0; i < 4; ++i) {
        int r = mt * 128 + wr * 64 + mf * 16 + hi * 4 + i;
        if (r >= M_) continue;
        int b = r / (T_ * J_);
        int rem = r - b * (T_ * J_);
        int t = rem / J_;
        int j = rem - t * J_;
        size_t rowoff = (((size_t)(b * H_ + h) * J_ + j) * T_ + t) * HD_;
        #pragma unroll
        for (int nf = 0; nf < 4; ++nf) {
          int hd = nf * 16 + lo;
          basep[rowoff + hd] = f2bf(acc[mf][nf][i] * scale);
        }
      }
    }
  } else {
    #pragma unroll
    for (int mf = 0; mf < 4; ++mf) {
      #pragma unroll
      for (int i = 0; i < 4; ++i) {
        int r = mt * 128 + wr * 64 + mf * 16 + hi * 4 + i;
        if (r >= M_) continue;
        #pragma unroll
        for (int nf = 0; nf < 4; ++nf) {
          int n = nt * 128 + wc * 64 + nf * 16 + lo;
          fout[(size_t)r * C_ + n] = acc[mf][nf][i] + bias[n];
        }
      }
    }
  }
}

// ---------------- flash: pure w*softmax(QK^T)@V, one block per (b,h,j,rt) ----------------
// writes O2[bhj][t][hd] bf16 (already scaled by w)
__global__ __launch_bounds__(256, 3) void flash_kernel(
    const ushort* __restrict__ q, const ushort* __restrict__ k,
    const ushort* __restrict__ v, const float* __restrict__ wptr,
    ushort* __restrict__ O2)
{
  __shared__ ushort Vt[64 * 256];   // transposed V [hd][s], swizzled (32KB)
  __shared__ ushort Ps[64 * 128];   // P half-tile [row][s_local], swizzled (16KB)
  __shared__ float red0[2][64];
  __shared__ float red1[2][64];

  const int tid = threadIdx.x;
  const int lane = tid & 63;
  const int lo = lane & 15, hi = lane >> 4;
  const int wave = tid >> 6;
  const int wr = wave >> 1, wc = wave & 1;
  const int bid = blockIdx.x;
  const int workid = (bid & 7) * 544 + (bid >> 3);
  const int bhj = workid >> 2, rt = workid & 3;
  const float w = wptr[0];
  const size_t kvbase = (size_t)bhj * (T_ * HD_);
  const int r0 = rt * 64;

  #pragma unroll
  for (int it = 0; it < 8; ++it) {
    int c = tid + it * 256;
    int s = c >> 3, hd0 = (c & 7) * 8;
    bf16x8 val = {};
    if (s < T_) val = *(const bf16x8*)(v + kvbase + (size_t)s * HD_ + hd0);
    #pragma unroll
    for (int e = 0; e < 8; ++e) {
      int row = hd0 + e;
      int chunk = (s >> 3) ^ (row & 7);
      Vt[row * 256 + chunk * 8 + (s & 7)] = (ushort)val[e];
    }
  }
  __syncthreads();

  bf16x8 aq[2][2];
  #pragma unroll
  for (int mf = 0; mf < 2; ++mf) {
    int t = r0 + wr * 32 + mf * 16 + lo; if (t > T_ - 1) t = T_ - 1;
    #pragma unroll
    for (int kk = 0; kk < 2; ++kk)
      aq[mf][kk] = *(const bf16x8*)(q + kvbase + (size_t)t * HD_ + kk * 32 + hi * 8);
  }

  f32x4 acc[2][8] = {};
  #pragma unroll
  for (int nf = 0; nf < 8; ++nf) {
    int s = wc * 128 + nf * 16 + lo; if (s > T_ - 1) s = T_ - 1;
    #pragma unroll
    for (int kk = 0; kk < 2; ++kk) {
      bf16x8 bk = *(const bf16x8*)(k + kvbase + (size_t)s * HD_ + kk * 32 + hi * 8);
      #pragma unroll
      for (int mf = 0; mf < 2; ++mf)
        acc[mf][nf] = __builtin_amdgcn_mfma_f32_16x16x32_bf16(aq[mf][kk], bk, acc[mf][nf], 0, 0, 0);
    }
  }

  float rmax[2][4];
  #pragma unroll
  for (int mf = 0; mf < 2; ++mf)
    #pragma unroll
    for (int i = 0; i < 4; ++i) {
      float m = -1e30f;
      #pragma unroll
      for (int nf = 0; nf < 8; ++nf) {
        int s = wc * 128 + nf * 16 + lo;
        if (s < T_) m = fmaxf(m, acc[mf][nf][i]);
      }
      rmax[mf][i] = m;
    }
  #pragma unroll
  for (int d = 1; d < 16; d <<= 1)
    #pragma unroll
    for (int mf = 0; mf < 2; ++mf)
      #pragma unroll
      for (int i = 0; i < 4; ++i)
        rmax[mf][i] = fmaxf(rmax[mf][i], __shfl_xor(rmax[mf][i], d, 64));
  if (lo == 0) {
    #pragma unroll
    for (int mf = 0; mf < 2; ++mf)
      #pragma unroll
      for (int i = 0; i < 4; ++i)
        red0[wc][wr * 32 + mf * 16 + hi * 4 + i] = rmax[mf][i];
  }
  __syncthreads();

  float rsum[2][4];
  #pragma unroll
  for (int mf = 0; mf < 2; ++mf)
    #pragma unroll
    for (int i = 0; i < 4; ++i) {
      float Mx = fmaxf(rmax[mf][i], red0[wc ^ 1][wr * 32 + mf * 16 + hi * 4 + i]);
      float ssum = 0.f;
      #pragma unroll
      for (int nf = 0; nf < 8; ++nf) {
        int s = wc * 128 + nf * 16 + lo;
        float e = 0.f;
        if (s < T_) e = __expf(acc[mf][nf][i] - Mx);
        acc[mf][nf][i] = e;
        ssum += e;
      }
      rsum[mf][i] = ssum;
    }
  #pragma unroll
  for (int d = 1; d < 16; d <<= 1)
    #pragma unroll
    for (int mf = 0; mf < 2; ++mf)
      #pragma unroll
      for (int i = 0; i < 4; ++i)
        rsum[mf][i] += __shfl_xor(rsum[mf][i], d, 64);
  if (lo == 0) {
    #pragma unroll
    for (int mf = 0; mf < 2; ++mf)
      #pragma unroll
      for (int i = 0; i < 4; ++i)
        red1[wc][wr * 32 + mf * 16 + hi * 4 + i] = rsum[mf][i];
  }
  __syncthreads();

  float pinv[2][4];
  #pragma unroll
  for (int mf = 0; mf < 2; ++mf)
    #pragma unroll
    for (int i = 0; i < 4; ++i) {
      float L = rsum[mf][i] + red1[wc ^ 1][wr * 32 + mf * 16 + hi * 4 + i];
      pinv[mf][i] = w / L;
    }

  f32x4 oacc[2][2] = {};
  #pragma unroll
  for (int h2 = 0; h2 < 2; ++h2) {
    __syncthreads();
    if (wc == h2) {
      #pragma unroll
      for (int mf = 0; mf < 2; ++mf)
        #pragma unroll
        for (int i = 0; i < 4; ++i) {
          int row_local = wr * 32 + mf * 16 + hi * 4 + i;
          float pw = pinv[mf][i];
          #pragma unroll
          for (int nf = 0; nf < 8; ++nf) {
            int s = h2 * 128 + nf * 16 + lo;
            float p = (s < T_) ? acc[mf][nf][i] * pw : 0.f;
            int s_local = nf * 16 + lo;
            int chunk = (s_local >> 3) ^ (row_local & 7);
            Ps[row_local * 128 + chunk * 8 + (s_local & 7)] = f2bf(p);
          }
        }
    }
    __syncthreads();
    #pragma unroll
    for (int kk = 0; kk < 4; ++kk) {
      bf16x8 ap[2], bv[2];
      #pragma unroll
      for (int mf = 0; mf < 2; ++mf) {
        int row = wr * 32 + mf * 16 + lo;
        int chunk = (kk * 4 + hi) ^ (row & 7);
        ap[mf] = *(const bf16x8*)(Ps + row * 128 + chunk * 8);
      }
      #pragma unroll
      for (int nf = 0; nf < 2; ++nf) {
        int row = wc * 32 + nf * 16 + lo;
        int chunk = ((h2 * 4 + kk) * 4 + hi) ^ (row & 7);
        bv[nf] = *(const bf16x8*)(Vt + row * 256 + chunk * 8);
      }
      #pragma unroll
      for (int mf = 0; mf < 2; ++mf)
        #pragma unroll
        for (int nf = 0; nf < 2; ++nf)
          oacc[mf][nf] = __builtin_amdgcn_mfma_f32_16x16x32_bf16(ap[mf], bv[nf], oacc[mf][nf], 0, 0, 0);
    }
  }

  #pragma unroll
  for (int mf = 0; mf < 2; ++mf)
    #pragma unroll
    for (int i = 0; i < 4; ++i) {
      int t = r0 + wr * 32 + mf * 16 + hi * 4 + i;
      if (t >= T_) continue;
      size_t rowoff = ((size_t)bhj * T_ + t) * HD_;
      #pragma unroll
      for (int nf = 0; nf < 2; ++nf) {
        int hd = wc * 32 + nf * 16 + lo;
        O2[rowoff + hd] = f2bf(oacc[mf][nf][i]);
      }
    }
}

// ---------------- amv v2: O = (1-w)*(am@V) + O2, one block per (b,h,j,rt) ----------------
// am loaded DIRECTLY from global into MFMA fragments (no LDS staging)
__global__ __launch_bounds__(256, 4) void amv_kernel(
    const float* __restrict__ am, const ushort* __restrict__ v,
    const ushort* __restrict__ o2, const float* __restrict__ wptr,
    ushort* __restrict__ outO)
{
  __shared__ ushort Vt[64 * 256];   // transposed V [hd][s], swizzled (32KB)

  const int tid = threadIdx.x;
  const int lane = tid & 63;
  const int lo = lane & 15, hi = lane >> 4;
  const int wave = tid >> 6;
  const int wr = wave >> 1, wc = wave & 1;
  const int bid = blockIdx.x;
  const int workid = (bid & 7) * 544 + (bid >> 3);   // XCD chunking, grid 4352
  const int bhj = workid >> 2, rt = workid & 3;
  const int bh = bhj / J_, j = bhj - bh * J_;
  const int b = bh >> 3, h = bh & 7;
  const float wb = 1.0f - wptr[0];
  const size_t kvbase = (size_t)bhj * (T_ * HD_);
  const int r0 = rt * 64;

  // stage V transposed + zero-padded
  #pragma unroll
  for (int it = 0; it < 8; ++it) {
    int c = tid + it * 256;
    int s = c >> 3, hd0 = (c & 7) * 8;
    bf16x8 val = {};
    if (s < T_) val = *(const bf16x8*)(v + kvbase + (size_t)s * HD_ + hd0);
    #pragma unroll
    for (int e = 0; e < 8; ++e) {
      int row = hd0 + e;
      int chunk = (s >> 3) ^ (row & 7);
      Vt[row * 256 + chunk * 8 + (s & 7)] = (ushort)val[e];
    }
  }
  __syncthreads();

  // per-lane am row pointers (A-fragment rows)
  const float* amrow[2];
  #pragma unroll
  for (int mf = 0; mf < 2; ++mf) {
    int t = r0 + wr * 32 + mf * 16 + lo; if (t > T_ - 1) t = T_ - 1;
    amrow[mf] = am + (size_t)bhj * (T_ * T_) + (size_t)t * T_;
  }

  f32x4 acc[2][2] = {};
  #pragma unroll
  for (int kk = 0; kk < 8; ++kk) {
    const int s8 = kk * 32 + hi * 8;
    bf16x8 aa[2];
    #pragma unroll
    for (int mf = 0; mf < 2; ++mf) {
      bf16x8 r;
      if (s8 + 7 <= T_ - 1) {          // uniform per (kk,hi)
        #pragma unroll
        for (int e = 0; e < 8; ++e) r[e] = (short)f2bf(amrow[mf][s8 + e]);
      } else {
        #pragma unroll
        for (int e = 0; e < 8; ++e) {
          int s = s8 + e;
          r[e] = (s <= T_ - 1) ? (short)f2bf(amrow[mf][s]) : (short)0;
        }
      }
      aa[mf] = r;
    }
    bf16x8 bv[2];
    #pragma unroll
    for (int nf = 0; nf < 2; ++nf) {
      int row = wc * 32 + nf * 16 + lo;   // hd
      int chunk = (kk * 4 + hi) ^ (row & 7);
      bv[nf] = *(const bf16x8*)(Vt + row * 256 + chunk * 8);
    }
    #pragma unroll
    for (int mf = 0; mf < 2; ++mf)
      #pragma unroll
      for (int nf = 0; nf < 2; ++nf)
        acc[mf][nf] = __builtin_amdgcn_mfma_f32_16x16x32_bf16(aa[mf], bv[nf], acc[mf][nf], 0, 0, 0);
  }

  // epilogue: blend with O2 (w*SV) and write final O [B,T,J,C]
  #pragma unroll
  for (int mf = 0; mf < 2; ++mf)
    #pragma unroll
    for (int i = 0; i < 4; ++i) {
      int t = r0 + wr * 32 + mf * 16 + hi * 4 + i;
      if (t >= T_) continue;
      size_t o2row = ((size_t)bhj * T_ + t) * HD_;
      size_t orow = ((size_t)(b * T_ + t) * J_ + j) * C_ + h * HD_;
      #pragma unroll
      for (int nf = 0; nf < 2; ++nf) {
        int hd = wc * 32 + nf * 16 + lo;
        outO[orow + hd] = f2bf(wb * acc[mf][nf][i] + bf2f(o2[o2row + hd]));
      }
    }
}

// ---------------- launcher ----------------
extern "C" void kernel_launch(void* const* d_in, const int* in_sizes, int n_in,
                              void* d_out, int out_size, void* d_ws, size_t ws_size,
                              hipStream_t stream) {
  const float* x      = (const float*)d_in[0];
  const float* am     = (const float*)d_in[1];
  const float* weight = (const float*)d_in[2];
  const float* w_qkv  = (const float*)d_in[3];
  const float* w_proj = (const float*)d_in[4];
  const float* b_proj = (const float*)d_in[5];
  float* outp = (float*)d_out;

  char* ws = (char*)d_ws;
  ushort* wqkv_bf  = (ushort*)(ws);                  // 1,572,864 B
  ushort* wproj_bf = (ushort*)(ws + 1572864);        //   524,288 B
  ushort* xbf      = (ushort*)(ws + 2097152);        // 33,841,152 B (x bf16, reused as O2)
  ushort* qws      = (ushort*)(ws + 35938304);       // q, reused as final O [B,T,J,C]
  ushort* kws = qws + QKV_ELEMS;
  ushort* vws = kws + QKV_ELEMS;
  if (ws_size < 137461760ull) return;

  cvt_kernel<<<8262, 256, 0, stream>>>(x, xbf, 2115072);
  cvt_kernel<<<384, 256, 0, stream>>>(w_qkv, wqkv_bf, 98304);
  cvt_kernel<<<128, 256, 0, stream>>>(w_proj, wproj_bf, 32768);

  gemm_bt<0><<<dim3(259, 12), 256, 0, stream>>>(xbf, wqkv_bf, qws, nullptr, nullptr);

  // flash: q,k,v -> O2 (= w * softmax@V) into xbf region (x no longer needed)
  flash_kernel<<<4352, 256, 0, stream>>>(qws, kws, vws, weight, xbf);

  // amv v2: am,V,O2 -> final O into qws region (q no longer needed)
  amv_kernel<<<4352, 256, 0, stream>>>(am, vws, xbf, weight, qws);

  gemm_bt<1><<<dim3(259, 4), 256, 0, stream>>>(qws, wproj_bf, nullptr, outp, b_proj);
}

// Round 4
// 336.878 us; speedup vs baseline: 1.9261x; 1.0966x over previous
//
#include <hip/hip_runtime.h>
#include <hip/hip_bf16.h>

#define B_ 8
#define T_ 243
#define J_ 17
#define C_ 512
#define H_ 8
#define HD_ 64
#define M_ (B_*T_*J_)            // 33048
#define SCALE_ 0.125f
#define QKV_ELEMS (B_*H_*J_*T_*HD_)  // 16,920,576

typedef __attribute__((ext_vector_type(4))) float f32x4;
typedef __attribute__((ext_vector_type(8))) short bf16x8;

__device__ __forceinline__ ushort f2bf(float f) {
  union { float f; unsigned u; } v; v.f = f;
  unsigned r = v.u + 0x7FFFu + ((v.u >> 16) & 1u);
  return (ushort)(r >> 16);
}
__device__ __forceinline__ float bf2f(ushort u) {
  union { unsigned u; float f; } v; v.u = (unsigned)u << 16; return v.f;
}
// Vt swizzle: spreads BOTH the transpose-write (row&7 const, row>>3 varies)
// and the fragment-read (row&7 varies) patterns across banks.
__device__ __forceinline__ int vchunk(int g, int row) {
  return g ^ (row & 7) ^ ((row >> 3) & 7);
}

// ---------------- f32 -> bf16 convert (8 elems/thread) ----------------
__global__ __launch_bounds__(256) void cvt_kernel(const float* __restrict__ in,
                                                  ushort* __restrict__ out, int n8) {
  int i = blockIdx.x * 256 + threadIdx.x;
  if (i >= n8) return;
  const float4* p = (const float4*)in + (size_t)i * 2;
  float4 v0 = p[0], v1 = p[1];
  bf16x8 o;
  o[0] = (short)f2bf(v0.x); o[1] = (short)f2bf(v0.y);
  o[2] = (short)f2bf(v0.z); o[3] = (short)f2bf(v0.w);
  o[4] = (short)f2bf(v1.x); o[5] = (short)f2bf(v1.y);
  o[6] = (short)f2bf(v1.z); o[7] = (short)f2bf(v1.w);
  *(bf16x8*)(out + (size_t)i * 8) = o;
}

// ---------------- bf16 GEMM: C[M,N] = A[M,K=512] @ Bm[N,K=512]^T ----------------
template<int EPI>
__global__ __launch_bounds__(256) void gemm_bt(
    const ushort* __restrict__ A, const ushort* __restrict__ Bm,
    ushort* __restrict__ qkvout, float* __restrict__ fout,
    const float* __restrict__ bias)
{
  __shared__ ushort As[128 * 64];
  __shared__ ushort Bs[128 * 64];
  const int tid = threadIdx.x;
  const int lane = tid & 63;
  const int lo = lane & 15, hi = lane >> 4;
  const int wave = tid >> 6;
  const int wr = wave >> 1, wc = wave & 1;
  const int mt = blockIdx.x, nt = blockIdx.y;

  f32x4 acc[4][4] = {};

  for (int ks = 0; ks < 8; ++ks) {
    const int k0 = ks * 64;
    bf16x8 ra[4], rb[4];
    #pragma unroll
    for (int i = 0; i < 4; ++i) {
      int c = tid + i * 256;
      int row = c >> 3, col8 = c & 7;
      int arow = mt * 128 + row; if (arow > M_ - 1) arow = M_ - 1;
      ra[i] = *(const bf16x8*)(A + (size_t)arow * 512 + k0 + col8 * 8);
      int brow = nt * 128 + row;
      rb[i] = *(const bf16x8*)(Bm + (size_t)brow * 512 + k0 + col8 * 8);
    }
    __syncthreads();
    #pragma unroll
    for (int i = 0; i < 4; ++i) {
      int c = tid + i * 256;
      int row = c >> 3, col8 = c & 7;
      int sc = col8 ^ (row & 7);
      *(bf16x8*)(As + row * 64 + sc * 8) = ra[i];
      *(bf16x8*)(Bs + row * 64 + sc * 8) = rb[i];
    }
    __syncthreads();
    #pragma unroll
    for (int kk = 0; kk < 2; ++kk) {
      bf16x8 af[4], bf[4];
      #pragma unroll
      for (int mf = 0; mf < 4; ++mf) {
        int row = wr * 64 + mf * 16 + lo;
        int sc = (kk * 4 + hi) ^ (row & 7);
        af[mf] = *(const bf16x8*)(As + row * 64 + sc * 8);
      }
      #pragma unroll
      for (int nf = 0; nf < 4; ++nf) {
        int row = wc * 64 + nf * 16 + lo;
        int sc = (kk * 4 + hi) ^ (row & 7);
        bf[nf] = *(const bf16x8*)(Bs + row * 64 + sc * 8);
      }
      #pragma unroll
      for (int mf = 0; mf < 4; ++mf)
        #pragma unroll
        for (int nf = 0; nf < 4; ++nf)
          acc[mf][nf] = __builtin_amdgcn_mfma_f32_16x16x32_bf16(af[mf], bf[nf], acc[mf][nf], 0, 0, 0);
    }
  }

  if (EPI == 0) {
    const int which = nt >> 2;                 // 0=q 1=k 2=v
    const int h = (nt * 2 + wc) & 7;
    const float scale = (which == 0) ? SCALE_ : 1.0f;
    ushort* basep = qkvout + (size_t)which * QKV_ELEMS;
    #pragma unroll
    for (int mf = 0; mf < 4; ++mf) {
      #pragma unroll
      for (int i = 0; i < 4; ++i) {
        int r = mt * 128 + wr * 64 + mf * 16 + hi * 4 + i;
        if (r >= M_) continue;
        int b = r / (T_ * J_);
        int rem = r - b * (T_ * J_);
        int t = rem / J_;
        int j = rem - t * J_;
        size_t rowoff = (((size_t)(b * H_ + h) * J_ + j) * T_ + t) * HD_;
        #pragma unroll
        for (int nf = 0; nf < 4; ++nf) {
          int hd = nf * 16 + lo;
          basep[rowoff + hd] = f2bf(acc[mf][nf][i] * scale);
        }
      }
    }
  } else {
    #pragma unroll
    for (int mf = 0; mf < 4; ++mf) {
      #pragma unroll
      for (int i = 0; i < 4; ++i) {
        int r = mt * 128 + wr * 64 + mf * 16 + hi * 4 + i;
        if (r >= M_) continue;
        #pragma unroll
        for (int nf = 0; nf < 4; ++nf) {
          int n = nt * 128 + wc * 64 + nf * 16 + lo;
          fout[(size_t)r * C_ + n] = acc[mf][nf][i] + bias[n];
        }
      }
    }
  }
}

// ---------------- merged attn: O = w*softmax(QK^T)@V + (1-w)*am@V ----------------
// one block per (b,h,j,rt); writes final O in [B,T,J,C] bf16
__global__ __launch_bounds__(256, 3) void attn_kernel(
    const ushort* __restrict__ q, const ushort* __restrict__ k,
    const ushort* __restrict__ v, const float* __restrict__ am,
    const float* __restrict__ wptr, ushort* __restrict__ outO)
{
  __shared__ ushort Vt[64 * 256];   // transposed V [hd][s], vchunk-swizzled (32KB)
  __shared__ ushort Ps[64 * 128];   // P half-tile [row][s_local], swizzled (16KB)
  __shared__ float red0[2][64];
  __shared__ float red1[2][64];

  const int tid = threadIdx.x;
  const int lane = tid & 63;
  const int lo = lane & 15, hi = lane >> 4;
  const int wave = tid >> 6;
  const int wr = wave >> 1, wc = wave & 1;
  const int bid = blockIdx.x;
  const int workid = (bid & 7) * 544 + (bid >> 3);   // XCD chunking, grid 4352
  const int bhj = workid >> 2, rt = workid & 3;
  const int bh = bhj / J_, j = bhj - bh * J_;
  const int b = bh >> 3, h = bh & 7;
  const float w = wptr[0];
  const float wb = 1.0f - w;
  const size_t kvbase = (size_t)bhj * (T_ * HD_);
  const int r0 = rt * 64;

  // stage V transposed + zero-padded (conflict-free via vchunk)
  #pragma unroll
  for (int it = 0; it < 8; ++it) {
    int c = tid + it * 256;
    int s = c >> 3, hd0 = (c & 7) * 8;
    bf16x8 val = {};
    if (s < T_) val = *(const bf16x8*)(v + kvbase + (size_t)s * HD_ + hd0);
    #pragma unroll
    for (int e = 0; e < 8; ++e) {
      int row = hd0 + e;
      int chunk = vchunk(s >> 3, row);
      Vt[row * 256 + chunk * 8 + (s & 7)] = (ushort)val[e];
    }
  }
  __syncthreads();

  // Q fragments direct from global
  bf16x8 aq[2][2];
  #pragma unroll
  for (int mf = 0; mf < 2; ++mf) {
    int t = r0 + wr * 32 + mf * 16 + lo; if (t > T_ - 1) t = T_ - 1;
    #pragma unroll
    for (int kk = 0; kk < 2; ++kk)
      aq[mf][kk] = *(const bf16x8*)(q + kvbase + (size_t)t * HD_ + kk * 32 + hi * 8);
  }

  // QK^T
  f32x4 acc[2][8] = {};
  #pragma unroll
  for (int nf = 0; nf < 8; ++nf) {
    int s = wc * 128 + nf * 16 + lo; if (s > T_ - 1) s = T_ - 1;
    #pragma unroll
    for (int kk = 0; kk < 2; ++kk) {
      bf16x8 bk = *(const bf16x8*)(k + kvbase + (size_t)s * HD_ + kk * 32 + hi * 8);
      #pragma unroll
      for (int mf = 0; mf < 2; ++mf)
        acc[mf][nf] = __builtin_amdgcn_mfma_f32_16x16x32_bf16(aq[mf][kk], bk, acc[mf][nf], 0, 0, 0);
    }
  }

  // row max (mask s >= 243)
  float rmax[2][4];
  #pragma unroll
  for (int mf = 0; mf < 2; ++mf)
    #pragma unroll
    for (int i = 0; i < 4; ++i) {
      float m = -1e30f;
      #pragma unroll
      for (int nf = 0; nf < 8; ++nf) {
        int s = wc * 128 + nf * 16 + lo;
        if (s < T_) m = fmaxf(m, acc[mf][nf][i]);
      }
      rmax[mf][i] = m;
    }
  #pragma unroll
  for (int d = 1; d < 16; d <<= 1)
    #pragma unroll
    for (int mf = 0; mf < 2; ++mf)
      #pragma unroll
      for (int i = 0; i < 4; ++i)
        rmax[mf][i] = fmaxf(rmax[mf][i], __shfl_xor(rmax[mf][i], d, 64));
  if (lo == 0) {
    #pragma unroll
    for (int mf = 0; mf < 2; ++mf)
      #pragma unroll
      for (int i = 0; i < 4; ++i)
        red0[wc][wr * 32 + mf * 16 + hi * 4 + i] = rmax[mf][i];
  }
  __syncthreads();

  // exp + row sum
  float rsum[2][4];
  #pragma unroll
  for (int mf = 0; mf < 2; ++mf)
    #pragma unroll
    for (int i = 0; i < 4; ++i) {
      float Mx = fmaxf(rmax[mf][i], red0[wc ^ 1][wr * 32 + mf * 16 + hi * 4 + i]);
      float ssum = 0.f;
      #pragma unroll
      for (int nf = 0; nf < 8; ++nf) {
        int s = wc * 128 + nf * 16 + lo;
        float e = 0.f;
        if (s < T_) e = __expf(acc[mf][nf][i] - Mx);
        acc[mf][nf][i] = e;
        ssum += e;
      }
      rsum[mf][i] = ssum;
    }
  #pragma unroll
  for (int d = 1; d < 16; d <<= 1)
    #pragma unroll
    for (int mf = 0; mf < 2; ++mf)
      #pragma unroll
      for (int i = 0; i < 4; ++i)
        rsum[mf][i] += __shfl_xor(rsum[mf][i], d, 64);
  if (lo == 0) {
    #pragma unroll
    for (int mf = 0; mf < 2; ++mf)
      #pragma unroll
      for (int i = 0; i < 4; ++i)
        red1[wc][wr * 32 + mf * 16 + hi * 4 + i] = rsum[mf][i];
  }
  __syncthreads();

  float pinv[2][4];
  #pragma unroll
  for (int mf = 0; mf < 2; ++mf)
    #pragma unroll
    for (int i = 0; i < 4; ++i) {
      float L = rsum[mf][i] + red1[wc ^ 1][wr * 32 + mf * 16 + hi * 4 + i];
      pinv[mf][i] = w / L;   // fold blend weight into P
    }

  // PV in two s-halves through half-size Ps
  f32x4 oacc[2][2] = {};
  #pragma unroll
  for (int h2 = 0; h2 < 2; ++h2) {
    __syncthreads();
    if (wc == h2) {
      #pragma unroll
      for (int mf = 0; mf < 2; ++mf)
        #pragma unroll
        for (int i = 0; i < 4; ++i) {
          int row_local = wr * 32 + mf * 16 + hi * 4 + i;
          float pw = pinv[mf][i];
          #pragma unroll
          for (int nf = 0; nf < 8; ++nf) {
            int s = h2 * 128 + nf * 16 + lo;
            float p = (s < T_) ? acc[mf][nf][i] * pw : 0.f;
            int s_local = nf * 16 + lo;
            int chunk = (s_local >> 3) ^ (row_local & 7);
            Ps[row_local * 128 + chunk * 8 + (s_local & 7)] = f2bf(p);
          }
        }
    }
    __syncthreads();
    #pragma unroll
    for (int kk = 0; kk < 4; ++kk) {
      bf16x8 ap[2], bv[2];
      #pragma unroll
      for (int mf = 0; mf < 2; ++mf) {
        int row = wr * 32 + mf * 16 + lo;
        int chunk = (kk * 4 + hi) ^ (row & 7);
        ap[mf] = *(const bf16x8*)(Ps + row * 128 + chunk * 8);
      }
      #pragma unroll
      for (int nf = 0; nf < 2; ++nf) {
        int row = wc * 32 + nf * 16 + lo;   // hd
        int chunk = vchunk((h2 * 4 + kk) * 4 + hi, row);
        bv[nf] = *(const bf16x8*)(Vt + row * 256 + chunk * 8);
      }
      #pragma unroll
      for (int mf = 0; mf < 2; ++mf)
        #pragma unroll
        for (int nf = 0; nf < 2; ++nf)
          oacc[mf][nf] = __builtin_amdgcn_mfma_f32_16x16x32_bf16(ap[mf], bv[nf], oacc[mf][nf], 0, 0, 0);
    }
  }

  // am @ V (reuses Vt; no LDS writes pending so no barrier needed)
  const float* amrow[2];
  #pragma unroll
  for (int mf = 0; mf < 2; ++mf) {
    int t = r0 + wr * 32 + mf * 16 + lo; if (t > T_ - 1) t = T_ - 1;
    amrow[mf] = am + (size_t)bhj * (T_ * T_) + (size_t)t * T_;
  }
  f32x4 amacc[2][2] = {};
  #pragma unroll
  for (int kk = 0; kk < 8; ++kk) {
    const int s8 = kk * 32 + hi * 8;
    bf16x8 aa[2];
    #pragma unroll
    for (int mf = 0; mf < 2; ++mf) {
      bf16x8 r;
      if (s8 + 7 <= T_ - 1) {
        #pragma unroll
        for (int e = 0; e < 8; ++e) r[e] = (short)f2bf(amrow[mf][s8 + e]);
      } else {
        #pragma unroll
        for (int e = 0; e < 8; ++e) {
          int s = s8 + e;
          r[e] = (s <= T_ - 1) ? (short)f2bf(amrow[mf][s]) : (short)0;
        }
      }
      aa[mf] = r;
    }
    bf16x8 bv[2];
    #pragma unroll
    for (int nf = 0; nf < 2; ++nf) {
      int row = wc * 32 + nf * 16 + lo;   // hd
      int chunk = vchunk(kk * 4 + hi, row);
      bv[nf] = *(const bf16x8*)(Vt + row * 256 + chunk * 8);
    }
    #pragma unroll
    for (int mf = 0; mf < 2; ++mf)
      #pragma unroll
      for (int nf = 0; nf < 2; ++nf)
        amacc[mf][nf] = __builtin_amdgcn_mfma_f32_16x16x32_bf16(aa[mf], bv[nf], amacc[mf][nf], 0, 0, 0);
  }

  // epilogue: O = w*SV + (1-w)*amV, write [B,T,J,C] bf16
  #pragma unroll
  for (int mf = 0; mf < 2; ++mf)
    #pragma unroll
    for (int i = 0; i < 4; ++i) {
      int t = r0 + wr * 32 + mf * 16 + hi * 4 + i;
      if (t >= T_) continue;
      size_t orow = ((size_t)(b * T_ + t) * J_ + j) * C_ + h * HD_;
      #pragma unroll
      for (int nf = 0; nf < 2; ++nf) {
        int hd = wc * 32 + nf * 16 + lo;
        outO[orow + hd] = f2bf(oacc[mf][nf][i] + wb * amacc[mf][nf][i]);
      }
    }
}

// ---------------- launcher ----------------
extern "C" void kernel_launch(void* const* d_in, const int* in_sizes, int n_in,
                              void* d_out, int out_size, void* d_ws, size_t ws_size,
                              hipStream_t stream) {
  const float* x      = (const float*)d_in[0];
  const float* am     = (const float*)d_in[1];
  const float* weight = (const float*)d_in[2];
  const float* w_qkv  = (const float*)d_in[3];
  const float* w_proj = (const float*)d_in[4];
  const float* b_proj = (const float*)d_in[5];
  float* outp = (float*)d_out;

  char* ws = (char*)d_ws;
  ushort* wqkv_bf  = (ushort*)(ws);                  // 1,572,864 B
  ushort* wproj_bf = (ushort*)(ws + 1572864);        //   524,288 B
  ushort* xbf      = (ushort*)(ws + 2097152);        // 33,841,152 B (x bf16, reused as final O)
  ushort* qws      = (ushort*)(ws + 35938304);
  ushort* kws = qws + QKV_ELEMS;
  ushort* vws = kws + QKV_ELEMS;
  if (ws_size < 137461760ull) return;

  cvt_kernel<<<8262, 256, 0, stream>>>(x, xbf, 2115072);
  cvt_kernel<<<384, 256, 0, stream>>>(w_qkv, wqkv_bf, 98304);
  cvt_kernel<<<128, 256, 0, stream>>>(w_proj, wproj_bf, 32768);

  gemm_bt<0><<<dim3(259, 12), 256, 0, stream>>>(xbf, wqkv_bf, qws, nullptr, nullptr);

  // merged attention: writes final O into xbf (x dead after gemm_qkv; q/k/v untouched)
  attn_kernel<<<4352, 256, 0, stream>>>(qws, kws, vws, am, weight, xbf);

  gemm_bt<1><<<dim3(259, 4), 256, 0, stream>>>(xbf, wproj_bf, nullptr, outp, b_proj);
}